// Round 2
// baseline (350.291 us; speedup 1.0000x reference)
//
#include <hip/hip_runtime.h>
#include <hip/hip_bf16.h>
#include <stdint.h>

typedef unsigned short u16;
typedef unsigned int u32;
typedef short s16x8 __attribute__((ext_vector_type(8)));
typedef short s16x4 __attribute__((ext_vector_type(4)));
typedef float f32x4 __attribute__((ext_vector_type(4)));

#define MFMA(a, b, c) __builtin_amdgcn_mfma_f32_16x16x32_bf16((a), (b), (c), 0, 0, 0)

__device__ __forceinline__ float bf2f(u16 h) {
  u32 u = ((u32)h) << 16;
  float f;
  __builtin_memcpy(&f, &u, 4);
  return f;
}
__device__ __forceinline__ u16 f2bf(float f) {
  u32 u;
  __builtin_memcpy(&u, &f, 4);
  u32 r = (u + 0x7FFFu + ((u >> 16) & 1u)) >> 16;
  return (u16)r;
}

// ---------------- f32 -> bf16 elementwise (q_s) ----------------
__global__ __launch_bounds__(256) void k_cvt(const float* __restrict__ in,
                                             u16* __restrict__ out, int n8) {
  int i = blockIdx.x * 256 + threadIdx.x;
  if (i >= n8) return;
  const f32x4* p = (const f32x4*)(in + (size_t)i * 8);
  f32x4 a = p[0], b = p[1];
  s16x8 o;
  for (int k = 0; k < 4; ++k) o[k] = (short)f2bf(a[k]);
  for (int k = 0; k < 4; ++k) o[4 + k] = (short)f2bf(b[k]);
  *(s16x8*)(out + (size_t)i * 8) = o;
}

// ---------------- transpose 1024x1024 f32 weights -> bf16 ----------------
__global__ __launch_bounds__(256) void k_transpose1024(const float* __restrict__ in,
                                                       u16* __restrict__ out) {
  __shared__ u16 tile[64][65];
  const int t = threadIdx.x, tx = t & 63, ty = t >> 6;
  const int r0 = blockIdx.y * 64, c0 = blockIdx.x * 64;
  for (int rr = 0; rr < 16; ++rr) {
    int row = rr * 4 + ty;
    tile[row][tx] = f2bf(in[(size_t)(r0 + row) * 1024 + c0 + tx]);
  }
  __syncthreads();
  for (int rr = 0; rr < 16; ++rr) {
    int row = rr * 4 + ty;
    out[(size_t)(c0 + row) * 1024 + r0 + tx] = tile[tx][row];
  }
}

// ---------------- transpose V (bf16) -> Vt[b,h,d,j] ----------------
__global__ __launch_bounds__(256) void k_transpose_v(const u16* __restrict__ V,
                                                     u16* __restrict__ Vt) {
  __shared__ u16 tile[64][65];
  const int t = threadIdx.x, tx = t & 63, ty = t >> 6;
  const int j0 = blockIdx.x * 64;
  const int bh = blockIdx.y, b = bh >> 4, h = bh & 15;
  const u16* src = V + (size_t)b * 2048 * 1024 + h * 64;
  u16* dst = Vt + (size_t)bh * 64 * 2048;
  for (int rr = 0; rr < 16; ++rr) {
    int row = rr * 4 + ty;
    tile[row][tx] = src[(size_t)(j0 + row) * 1024 + tx];
  }
  __syncthreads();
  for (int rr = 0; rr < 16; ++rr) {
    int d = rr * 4 + ty;
    dst[(size_t)d * 2048 + j0 + tx] = tile[tx][d];
  }
}

// ---------------- fused QKV GEMM: Xbf[4096,1024] @ WT[3072,1024]^T ----------------
__global__ __launch_bounds__(256) void k_qkv_gemm(const u16* __restrict__ X,
                                                  const u16* __restrict__ WT,
                                                  const float* __restrict__ pos,
                                                  u16* __restrict__ Qb,
                                                  u16* __restrict__ Kb,
                                                  u16* __restrict__ Vb) {
  __shared__ u16 As[128 * 32];
  __shared__ u16 Bs[128 * 32];
  const int t = threadIdx.x;
  const int lane = t & 63, wid = t >> 6;
  const int wr = wid >> 1, wc = wid & 1;
  const int g = lane >> 4, lr = lane & 15;
  const int m0 = blockIdx.y * 128, n0 = blockIdx.x * 128;
  const int ra = t >> 2;
  const int k8 = (t & 3) * 8;

  f32x4 acc[4][4] = {};

  for (int k0 = 0; k0 < 1024; k0 += 32) {
    *(s16x8*)&As[ra * 32 + k8] = *(const s16x8*)&X[(size_t)(m0 + ra) * 1024 + k0 + k8];
    *(s16x8*)&As[(64 + ra) * 32 + k8] = *(const s16x8*)&X[(size_t)(m0 + 64 + ra) * 1024 + k0 + k8];
    *(s16x8*)&Bs[ra * 32 + k8] = *(const s16x8*)&WT[(size_t)(n0 + ra) * 1024 + k0 + k8];
    *(s16x8*)&Bs[(64 + ra) * 32 + k8] = *(const s16x8*)&WT[(size_t)(n0 + 64 + ra) * 1024 + k0 + k8];
    __syncthreads();
    s16x8 a[4], b[4];
    for (int mi = 0; mi < 4; ++mi) a[mi] = *(const s16x8*)&As[(wr * 64 + mi * 16 + lr) * 32 + g * 8];
    for (int nj = 0; nj < 4; ++nj) b[nj] = *(const s16x8*)&Bs[(wc * 64 + nj * 16 + lr) * 32 + g * 8];
    for (int mi = 0; mi < 4; ++mi)
      for (int nj = 0; nj < 4; ++nj)
        acc[mi][nj] = MFMA(a[mi], b[nj], acc[mi][nj]);
    __syncthreads();
  }

  for (int mi = 0; mi < 4; ++mi) {
    for (int nj = 0; nj < 4; ++nj) {
      const int n_g = n0 + wc * 64 + nj * 16 + lr;
      const int buf = n_g >> 10;
      const int col = n_g & 1023;
      u16* dst = (buf == 0) ? Qb : ((buf == 1) ? Kb : Vb);
      for (int r = 0; r < 4; ++r) {
        const int row = m0 + wr * 64 + mi * 16 + g * 4 + r;
        float v = acc[mi][nj][r];
        if (buf == 1) v += pos[(size_t)row * 1024 + col];
        dst[(size_t)row * 1024 + col] = f2bf(v);
      }
    }
  }
}

// ---------------- flash attention per (b,h) ----------------
__global__ __launch_bounds__(256) void k_attn(const u16* __restrict__ Q,
                                              const u16* __restrict__ Kc,
                                              const u16* __restrict__ Vt,
                                              u16* __restrict__ O) {
  const int t = threadIdx.x, lane = t & 63, wid = t >> 6;
  const int g = lane >> 4, lr = lane & 15;
  const int bh = blockIdx.y, b = bh >> 4, h = bh & 15;
  const int i0 = blockIdx.x * 64 + wid * 16;  // wave's 16 Q rows
  const size_t rowbase = (size_t)b * 2048 * 1024 + (size_t)h * 64;

  __shared__ u16 P[4][16 * 64];
  u16* Pw = P[wid];

  s16x8 aq[2];
  for (int c = 0; c < 2; ++c)
    aq[c] = *(const s16x8*)&Q[rowbase + (size_t)(i0 + lr) * 1024 + c * 32 + g * 8];

  f32x4 o_acc[4] = {};
  float m_run[4], l_run[4];
  for (int r = 0; r < 4; ++r) { m_run[r] = -1e30f; l_run[r] = 0.f; }

  const u16* Vth = Vt + (size_t)bh * 64 * 2048;

  for (int j0 = 0; j0 < 2048; j0 += 64) {
    f32x4 s[4] = {};
    for (int jf = 0; jf < 4; ++jf) {
      for (int c = 0; c < 2; ++c) {
        s16x8 bk = *(const s16x8*)&Kc[rowbase + (size_t)(j0 + jf * 16 + lr) * 1024 + c * 32 + g * 8];
        s[jf] = MFMA(aq[c], bk, s[jf]);
      }
    }
    for (int jf = 0; jf < 4; ++jf)
      for (int r = 0; r < 4; ++r) s[jf][r] *= 0.125f;

    float mnew[4], alpha[4], psum[4];
    for (int r = 0; r < 4; ++r) {
      float tm = fmaxf(fmaxf(s[0][r], s[1][r]), fmaxf(s[2][r], s[3][r]));
      for (int m = 1; m < 16; m <<= 1) tm = fmaxf(tm, __shfl_xor(tm, m, 64));
      mnew[r] = fmaxf(m_run[r], tm);
      alpha[r] = __expf(m_run[r] - mnew[r]);
      psum[r] = 0.f;
    }
    for (int jf = 0; jf < 4; ++jf)
      for (int r = 0; r < 4; ++r) {
        float p = __expf(s[jf][r] - mnew[r]);
        s[jf][r] = p;
        psum[r] += p;
      }
    for (int r = 0; r < 4; ++r) {
      for (int m = 1; m < 16; m <<= 1) psum[r] += __shfl_xor(psum[r], m, 64);
      l_run[r] = l_run[r] * alpha[r] + psum[r];
      m_run[r] = mnew[r];
    }
    for (int df = 0; df < 4; ++df)
      for (int r = 0; r < 4; ++r) o_acc[df][r] *= alpha[r];

    for (int jf = 0; jf < 4; ++jf)
      for (int r = 0; r < 4; ++r)
        Pw[(g * 4 + r) * 64 + jf * 16 + lr] = f2bf(s[jf][r]);

    s16x8 pa[2];
    for (int c = 0; c < 2; ++c)
      pa[c] = *(const s16x8*)&Pw[lr * 64 + c * 32 + g * 8];

    for (int df = 0; df < 4; ++df) {
      for (int c = 0; c < 2; ++c) {
        s16x8 bv = *(const s16x8*)&Vth[(size_t)(df * 16 + lr) * 2048 + j0 + c * 32 + g * 8];
        o_acc[df] = MFMA(pa[c], bv, o_acc[df]);
      }
    }
  }

  for (int df = 0; df < 4; ++df)
    for (int r = 0; r < 4; ++r) {
      const int row = i0 + g * 4 + r;
      float v = o_acc[df][r] / l_run[r];
      O[rowbase + (size_t)row * 1024 + df * 16 + lr] = f2bf(v);
    }
}

// ---------------- out GEMM: O @ Wo + bo + q_s -> X (f32) ----------------
__global__ __launch_bounds__(256) void k_out_gemm(const u16* __restrict__ A,
                                                  const u16* __restrict__ WTo,
                                                  const float* __restrict__ bo,
                                                  const float* __restrict__ qs,
                                                  float* __restrict__ X) {
  __shared__ u16 As[128 * 32];
  __shared__ u16 Bs[128 * 32];
  const int t = threadIdx.x;
  const int lane = t & 63, wid = t >> 6;
  const int wr = wid >> 1, wc = wid & 1;
  const int g = lane >> 4, lr = lane & 15;
  const int m0 = blockIdx.y * 128, n0 = blockIdx.x * 128;
  const int ra = t >> 2;
  const int k8 = (t & 3) * 8;

  f32x4 acc[4][4] = {};

  for (int k0 = 0; k0 < 1024; k0 += 32) {
    *(s16x8*)&As[ra * 32 + k8] = *(const s16x8*)&A[(size_t)(m0 + ra) * 1024 + k0 + k8];
    *(s16x8*)&As[(64 + ra) * 32 + k8] = *(const s16x8*)&A[(size_t)(m0 + 64 + ra) * 1024 + k0 + k8];
    *(s16x8*)&Bs[ra * 32 + k8] = *(const s16x8*)&WTo[(size_t)(n0 + ra) * 1024 + k0 + k8];
    *(s16x8*)&Bs[(64 + ra) * 32 + k8] = *(const s16x8*)&WTo[(size_t)(n0 + 64 + ra) * 1024 + k0 + k8];
    __syncthreads();
    s16x8 a[4], b[4];
    for (int mi = 0; mi < 4; ++mi) a[mi] = *(const s16x8*)&As[(wr * 64 + mi * 16 + lr) * 32 + g * 8];
    for (int nj = 0; nj < 4; ++nj) b[nj] = *(const s16x8*)&Bs[(wc * 64 + nj * 16 + lr) * 32 + g * 8];
    for (int mi = 0; mi < 4; ++mi)
      for (int nj = 0; nj < 4; ++nj)
        acc[mi][nj] = MFMA(a[mi], b[nj], acc[mi][nj]);
    __syncthreads();
  }

  for (int mi = 0; mi < 4; ++mi) {
    for (int nj = 0; nj < 4; ++nj) {
      const int col = n0 + wc * 64 + nj * 16 + lr;
      for (int r = 0; r < 4; ++r) {
        const int row = m0 + wr * 64 + mi * 16 + g * 4 + r;
        float v = acc[mi][nj][r] + bo[col] + qs[(size_t)row * 1024 + col];
        X[(size_t)row * 1024 + col] = v;
      }
    }
  }
}

// ---------------- LayerNorm rows of 1024 (f32 in, f32 out) ----------------
__global__ __launch_bounds__(256) void k_ln(const float* __restrict__ X,
                                            const float* __restrict__ gg,
                                            const float* __restrict__ bb,
                                            float* __restrict__ out) {
  const int row = blockIdx.x, t = threadIdx.x;
  const int wid = t >> 6, lane = t & 63;
  const float* xr = X + (size_t)row * 1024;
  f32x4 x = *(const f32x4*)&xr[t * 4];
  float s1 = x[0] + x[1] + x[2] + x[3];
  float s2 = x[0] * x[0] + x[1] * x[1] + x[2] * x[2] + x[3] * x[3];
  for (int off = 32; off > 0; off >>= 1) {
    s1 += __shfl_down(s1, off, 64);
    s2 += __shfl_down(s2, off, 64);
  }
  __shared__ float red[2][4];
  if (lane == 0) { red[0][wid] = s1; red[1][wid] = s2; }
  __syncthreads();
  s1 = red[0][0] + red[0][1] + red[0][2] + red[0][3];
  s2 = red[1][0] + red[1][1] + red[1][2] + red[1][3];
  const float mu = s1 * (1.f / 1024.f);
  const float var = s2 * (1.f / 1024.f) - mu * mu;
  const float rstd = rsqrtf(var + 1e-5f);
  f32x4 gv = *(const f32x4*)&gg[t * 4];
  f32x4 bv = *(const f32x4*)&bb[t * 4];
  f32x4 ov;
  for (int i = 0; i < 4; ++i) ov[i] = (x[i] - mu) * rstd * gv[i] + bv[i];
  *(f32x4*)&out[(size_t)row * 1024 + t * 4] = ov;
}

extern "C" void kernel_launch(void* const* d_in, const int* in_sizes, int n_in,
                              void* d_out, int out_size, void* d_ws, size_t ws_size,
                              hipStream_t stream) {
  (void)in_sizes; (void)n_in; (void)out_size; (void)ws_size;
  const float* q_s = (const float*)d_in[0];
  const float* pos = (const float*)d_in[1];
  const float* Wq = (const float*)d_in[2];
  const float* Wk = (const float*)d_in[3];
  const float* Wv = (const float*)d_in[4];
  const float* Wo = (const float*)d_in[5];
  const float* bo = (const float*)d_in[6];
  const float* lng = (const float*)d_in[7];
  const float* lnb = (const float*)d_in[8];
  float* out = (float*)d_out;

  u16* ws = (u16*)d_ws;
  const size_t MB1 = 1024 * 1024;  // elements
  u16* WT  = ws;                   // 4 x 1M bf16 (Wq^T,Wk^T,Wv^T,Wo^T)
  u16* Xbf = ws + 4 * MB1;         // 4M bf16 (q_s as bf16)
  u16* Qb  = Xbf + 4 * MB1;
  u16* Kb  = Qb + 4 * MB1;
  u16* Vb  = Kb + 4 * MB1;
  u16* Vt  = Vb + 4 * MB1;
  u16* Ob  = Vt + 4 * MB1;
  float* Xb = (float*)Qb;          // f32 pre-LN x, aliases Qb+Kb (dead after attn)

  dim3 blk(256);
  k_cvt<<<dim3(2048), blk, 0, stream>>>(q_s, Xbf, 4 * MB1 / 8);
  k_transpose1024<<<dim3(16, 16), blk, 0, stream>>>(Wq, WT);
  k_transpose1024<<<dim3(16, 16), blk, 0, stream>>>(Wk, WT + MB1);
  k_transpose1024<<<dim3(16, 16), blk, 0, stream>>>(Wv, WT + 2 * MB1);
  k_transpose1024<<<dim3(16, 16), blk, 0, stream>>>(Wo, WT + 3 * MB1);
  k_qkv_gemm<<<dim3(24, 32), blk, 0, stream>>>(Xbf, WT, pos, Qb, Kb, Vb);
  k_transpose_v<<<dim3(32, 32), blk, 0, stream>>>(Vb, Vt);
  k_attn<<<dim3(32, 32), blk, 0, stream>>>(Qb, Kb, Vt, Ob);
  k_out_gemm<<<dim3(8, 32), blk, 0, stream>>>(Ob, WT + 3 * MB1, bo, q_s, Xb);
  k_ln<<<4096, blk, 0, stream>>>(Xb, lng, lnb, out);
}

// Round 3
// 237.948 us; speedup vs baseline: 1.4721x; 1.4721x over previous
//
#include <hip/hip_runtime.h>
#include <hip/hip_bf16.h>
#include <stdint.h>

typedef unsigned short u16;
typedef unsigned int u32;
typedef short s16x8 __attribute__((ext_vector_type(8)));
typedef short s16x4 __attribute__((ext_vector_type(4)));
typedef float f32x4 __attribute__((ext_vector_type(4)));

#define MFMA(a, b, c) __builtin_amdgcn_mfma_f32_16x16x32_bf16((a), (b), (c), 0, 0, 0)

__device__ __forceinline__ float bf2f(u16 h) {
  u32 u = ((u32)h) << 16;
  float f;
  __builtin_memcpy(&f, &u, 4);
  return f;
}
__device__ __forceinline__ u16 f2bf(float f) {
  u32 u;
  __builtin_memcpy(&u, &f, 4);
  u32 r = (u + 0x7FFFu + ((u >> 16) & 1u)) >> 16;
  return (u16)r;
}

// ---------------- f32 -> bf16 elementwise (q_s) ----------------
__global__ __launch_bounds__(256) void k_cvt(const float* __restrict__ in,
                                             u16* __restrict__ out, int n8) {
  int i = blockIdx.x * 256 + threadIdx.x;
  if (i >= n8) return;
  const f32x4* p = (const f32x4*)(in + (size_t)i * 8);
  f32x4 a = p[0], b = p[1];
  s16x8 o;
  for (int k = 0; k < 4; ++k) o[k] = (short)f2bf(a[k]);
  for (int k = 0; k < 4; ++k) o[4 + k] = (short)f2bf(b[k]);
  *(s16x8*)(out + (size_t)i * 8) = o;
}

// ---------------- transpose 1024x1024 f32 weights -> bf16 ----------------
__global__ __launch_bounds__(256) void k_transpose1024(const float* __restrict__ in,
                                                       u16* __restrict__ out) {
  __shared__ u16 tile[64][65];
  const int t = threadIdx.x, tx = t & 63, ty = t >> 6;
  const int r0 = blockIdx.y * 64, c0 = blockIdx.x * 64;
  for (int rr = 0; rr < 16; ++rr) {
    int row = rr * 4 + ty;
    tile[row][tx] = f2bf(in[(size_t)(r0 + row) * 1024 + c0 + tx]);
  }
  __syncthreads();
  for (int rr = 0; rr < 16; ++rr) {
    int row = rr * 4 + ty;
    out[(size_t)(c0 + row) * 1024 + r0 + tx] = tile[tx][row];
  }
}

// ---------------- transpose V [bh][2048][64] -> Vt[bh][64][2048] ----------------
__global__ __launch_bounds__(256) void k_transpose_v(const u16* __restrict__ V,
                                                     u16* __restrict__ Vt) {
  __shared__ u16 tile[64][65];
  const int t = threadIdx.x, tx = t & 63, ty = t >> 6;
  const int j0 = blockIdx.x * 64;
  const int bh = blockIdx.y;
  const u16* src = V + (size_t)bh * 2048 * 64;
  u16* dst = Vt + (size_t)bh * 64 * 2048;
  for (int rr = 0; rr < 16; ++rr) {
    int row = rr * 4 + ty;
    tile[row][tx] = src[(size_t)(j0 + row) * 64 + tx];
  }
  __syncthreads();
  for (int rr = 0; rr < 16; ++rr) {
    int d = rr * 4 + ty;
    dst[(size_t)d * 2048 + j0 + tx] = tile[tx][d];
  }
}

// ---------------- fused QKV GEMM -> packed per-head Q,K,V ----------------
// Q gets pre-scaled by 0.125 (attention scale). K gets pos added.
__global__ __launch_bounds__(256) void k_qkv_gemm(const u16* __restrict__ X,
                                                  const u16* __restrict__ WT,
                                                  const float* __restrict__ pos,
                                                  u16* __restrict__ Qh,
                                                  u16* __restrict__ Kh,
                                                  u16* __restrict__ Vh) {
  __shared__ u16 As[128 * 32];
  __shared__ u16 Bs[128 * 32];
  const int t = threadIdx.x;
  const int lane = t & 63, wid = t >> 6;
  const int wr = wid >> 1, wc = wid & 1;
  const int g = lane >> 4, lr = lane & 15;
  const int m0 = blockIdx.y * 128, n0 = blockIdx.x * 128;
  const int ra = t >> 2;
  const int k8 = (t & 3) * 8;

  f32x4 acc[4][4] = {};

  for (int k0 = 0; k0 < 1024; k0 += 32) {
    *(s16x8*)&As[ra * 32 + k8] = *(const s16x8*)&X[(size_t)(m0 + ra) * 1024 + k0 + k8];
    *(s16x8*)&As[(64 + ra) * 32 + k8] = *(const s16x8*)&X[(size_t)(m0 + 64 + ra) * 1024 + k0 + k8];
    *(s16x8*)&Bs[ra * 32 + k8] = *(const s16x8*)&WT[(size_t)(n0 + ra) * 1024 + k0 + k8];
    *(s16x8*)&Bs[(64 + ra) * 32 + k8] = *(const s16x8*)&WT[(size_t)(n0 + 64 + ra) * 1024 + k0 + k8];
    __syncthreads();
    s16x8 a[4], b[4];
    for (int mi = 0; mi < 4; ++mi) a[mi] = *(const s16x8*)&As[(wr * 64 + mi * 16 + lr) * 32 + g * 8];
    for (int nj = 0; nj < 4; ++nj) b[nj] = *(const s16x8*)&Bs[(wc * 64 + nj * 16 + lr) * 32 + g * 8];
    for (int mi = 0; mi < 4; ++mi)
      for (int nj = 0; nj < 4; ++nj)
        acc[mi][nj] = MFMA(a[mi], b[nj], acc[mi][nj]);
    __syncthreads();
  }

  for (int mi = 0; mi < 4; ++mi) {
    for (int nj = 0; nj < 4; ++nj) {
      const int n_g = n0 + wc * 64 + nj * 16 + lr;
      const int buf = n_g >> 10;       // 0=Q 1=K 2=V
      const int col = n_g & 1023;
      const int h = col >> 6, d = col & 63;
      u16* dst = (buf == 0) ? Qh : ((buf == 1) ? Kh : Vh);
      for (int r = 0; r < 4; ++r) {
        const int row = m0 + wr * 64 + mi * 16 + g * 4 + r;  // 0..4095
        const int b = row >> 11, n = row & 2047;
        float v = acc[mi][nj][r];
        if (buf == 1) v += pos[(size_t)row * 1024 + col];
        if (buf == 0) v *= 0.125f;
        dst[(size_t)((b * 16 + h) * 2048 + n) * 64 + d] = f2bf(v);
      }
    }
  }
}

// ---------------- flash attention per (b,h), LDS-staged K/V, swizzled ----------------
__global__ __launch_bounds__(256) void k_attn(const u16* __restrict__ Qh,
                                              const u16* __restrict__ Kh,
                                              const u16* __restrict__ Vt,
                                              u16* __restrict__ Oh) {
  const int t = threadIdx.x, lane = t & 63, wid = t >> 6;
  const int g = lane >> 4, lr = lane & 15;
  // bijective XCD swizzle: 1024 blocks, 8 XCDs -> each XCD gets 4 full bh panels
  const int hid = blockIdx.x;
  const int lid = (hid & 7) * 128 + (hid >> 3);
  const int bh = lid >> 5, itile = lid & 31;
  const int i0 = itile * 64 + wid * 16;  // wave's 16 Q rows

  __shared__ char Ks[64 * 128];   // [j][d] swizzled
  __shared__ char Vs[64 * 128];   // [d][j] swizzled
  __shared__ char Ps[4][16 * 128];  // per-wave P, swizzled
  char* Pw = Ps[wid];

  const u16* Qp = Qh + (size_t)bh * 2048 * 64;
  const u16* Kp = Kh + (size_t)bh * 2048 * 64;
  const u16* Vp = Vt + (size_t)bh * 64 * 2048;

  s16x8 aq[2];
  for (int c = 0; c < 2; ++c)
    aq[c] = *(const s16x8*)&Qp[(size_t)(i0 + lr) * 64 + c * 32 + g * 8];

  f32x4 o_acc[4] = {};
  float m_run[4], l_run[4];
  for (int r = 0; r < 4; ++r) { m_run[r] = -1e30f; l_run[r] = 0.f; }

  const int srow = t >> 3;        // 0..31 staging row
  const int sch = (t & 7) * 16;   // 16B chunk byte offset

  for (int j0 = 0; j0 < 2048; j0 += 64) {
    if (j0) __syncthreads();  // all waves done with previous K/V tile
    // stage K tile [64][64] and V tile [64][64], XOR-swizzled
    for (int half = 0; half < 2; ++half) {
      const int row = srow + half * 32;
      const int byte = (row * 128 + sch) ^ ((row & 7) << 4);
      *(s16x8*)(Ks + byte) = *(const s16x8*)&Kp[(size_t)(j0 + row) * 64 + (sch >> 1)];
      *(s16x8*)(Vs + byte) = *(const s16x8*)&Vp[(size_t)row * 2048 + j0 + (sch >> 1)];
    }
    __syncthreads();

    f32x4 s[4] = {};
    for (int jf = 0; jf < 4; ++jf) {
      const int row = jf * 16 + lr;
      for (int c = 0; c < 2; ++c) {
        const int byte = (row * 128 + c * 64 + g * 16) ^ ((row & 7) << 4);
        s16x8 bk = *(const s16x8*)(Ks + byte);
        s[jf] = MFMA(aq[c], bk, s[jf]);
      }
    }

    float mnew[4], alpha[4], psum[4];
    for (int r = 0; r < 4; ++r) {
      float tm = fmaxf(fmaxf(s[0][r], s[1][r]), fmaxf(s[2][r], s[3][r]));
      for (int m = 1; m < 16; m <<= 1) tm = fmaxf(tm, __shfl_xor(tm, m, 64));
      mnew[r] = fmaxf(m_run[r], tm);
      alpha[r] = __expf(m_run[r] - mnew[r]);
      psum[r] = 0.f;
    }
    for (int jf = 0; jf < 4; ++jf)
      for (int r = 0; r < 4; ++r) {
        float p = __expf(s[jf][r] - mnew[r]);
        s[jf][r] = p;
        psum[r] += p;
      }
    for (int r = 0; r < 4; ++r) {
      for (int m = 1; m < 16; m <<= 1) psum[r] += __shfl_xor(psum[r], m, 64);
      l_run[r] = l_run[r] * alpha[r] + psum[r];
      m_run[r] = mnew[r];
    }
    for (int df = 0; df < 4; ++df)
      for (int r = 0; r < 4; ++r) o_acc[df][r] *= alpha[r];

    // stage P through per-wave LDS (intra-wave ordering), swizzled
    for (int jf = 0; jf < 4; ++jf)
      for (int r = 0; r < 4; ++r) {
        const int row = g * 4 + r;
        const int byte = (row * 128 + (jf * 16 + lr) * 2) ^ ((row & 7) << 4);
        *(u16*)(Pw + byte) = f2bf(s[jf][r]);
      }

    s16x8 pa[2];
    for (int c = 0; c < 2; ++c) {
      const int byte = (lr * 128 + c * 64 + g * 16) ^ ((lr & 7) << 4);
      pa[c] = *(const s16x8*)(Pw + byte);
    }

    for (int df = 0; df < 4; ++df) {
      const int row = df * 16 + lr;
      for (int c = 0; c < 2; ++c) {
        const int byte = (row * 128 + c * 64 + g * 16) ^ ((row & 7) << 4);
        s16x8 bv = *(const s16x8*)(Vs + byte);
        o_acc[df] = MFMA(pa[c], bv, o_acc[df]);
      }
    }
  }

  for (int df = 0; df < 4; ++df)
    for (int r = 0; r < 4; ++r) {
      const int row = i0 + g * 4 + r;
      float v = o_acc[df][r] / l_run[r];
      Oh[(size_t)((size_t)bh * 2048 + row) * 64 + df * 16 + lr] = f2bf(v);
    }
}

// ---------------- out GEMM: Oh(packed) @ Wo + bo + q_s -> X (f32) ----------------
__global__ __launch_bounds__(256) void k_out_gemm(const u16* __restrict__ Oh,
                                                  const u16* __restrict__ WTo,
                                                  const float* __restrict__ bo,
                                                  const float* __restrict__ qs,
                                                  float* __restrict__ X) {
  __shared__ u16 As[128 * 32];
  __shared__ u16 Bs[128 * 32];
  const int t = threadIdx.x;
  const int lane = t & 63, wid = t >> 6;
  const int wr = wid >> 1, wc = wid & 1;
  const int g = lane >> 4, lr = lane & 15;
  const int m0 = blockIdx.y * 128, n0 = blockIdx.x * 128;
  const int ra = t >> 2;
  const int k8 = (t & 3) * 8;

  f32x4 acc[4][4] = {};

  for (int k0 = 0; k0 < 1024; k0 += 32) {
    const int h = k0 >> 6, d = (k0 & 63) + k8;
    {
      const int rg = m0 + ra, b = rg >> 11, n = rg & 2047;
      *(s16x8*)&As[ra * 32 + k8] = *(const s16x8*)&Oh[(size_t)((b * 16 + h) * 2048 + n) * 64 + d];
      const int rg2 = m0 + 64 + ra, b2 = rg2 >> 11, n2 = rg2 & 2047;
      *(s16x8*)&As[(64 + ra) * 32 + k8] = *(const s16x8*)&Oh[(size_t)((b2 * 16 + h) * 2048 + n2) * 64 + d];
    }
    *(s16x8*)&Bs[ra * 32 + k8] = *(const s16x8*)&WTo[(size_t)(n0 + ra) * 1024 + k0 + k8];
    *(s16x8*)&Bs[(64 + ra) * 32 + k8] = *(const s16x8*)&WTo[(size_t)(n0 + 64 + ra) * 1024 + k0 + k8];
    __syncthreads();
    s16x8 a[4], b[4];
    for (int mi = 0; mi < 4; ++mi) a[mi] = *(const s16x8*)&As[(wr * 64 + mi * 16 + lr) * 32 + g * 8];
    for (int nj = 0; nj < 4; ++nj) b[nj] = *(const s16x8*)&Bs[(wc * 64 + nj * 16 + lr) * 32 + g * 8];
    for (int mi = 0; mi < 4; ++mi)
      for (int nj = 0; nj < 4; ++nj)
        acc[mi][nj] = MFMA(a[mi], b[nj], acc[mi][nj]);
    __syncthreads();
  }

  for (int mi = 0; mi < 4; ++mi) {
    for (int nj = 0; nj < 4; ++nj) {
      const int col = n0 + wc * 64 + nj * 16 + lr;
      for (int r = 0; r < 4; ++r) {
        const int row = m0 + wr * 64 + mi * 16 + g * 4 + r;
        float v = acc[mi][nj][r] + bo[col] + qs[(size_t)row * 1024 + col];
        X[(size_t)row * 1024 + col] = v;
      }
    }
  }
}

// ---------------- LayerNorm rows of 1024 (f32 in, f32 out) ----------------
__global__ __launch_bounds__(256) void k_ln(const float* __restrict__ X,
                                            const float* __restrict__ gg,
                                            const float* __restrict__ bb,
                                            float* __restrict__ out) {
  const int row = blockIdx.x, t = threadIdx.x;
  const int wid = t >> 6, lane = t & 63;
  const float* xr = X + (size_t)row * 1024;
  f32x4 x = *(const f32x4*)&xr[t * 4];
  float s1 = x[0] + x[1] + x[2] + x[3];
  float s2 = x[0] * x[0] + x[1] * x[1] + x[2] * x[2] + x[3] * x[3];
  for (int off = 32; off > 0; off >>= 1) {
    s1 += __shfl_down(s1, off, 64);
    s2 += __shfl_down(s2, off, 64);
  }
  __shared__ float red[2][4];
  if (lane == 0) { red[0][wid] = s1; red[1][wid] = s2; }
  __syncthreads();
  s1 = red[0][0] + red[0][1] + red[0][2] + red[0][3];
  s2 = red[1][0] + red[1][1] + red[1][2] + red[1][3];
  const float mu = s1 * (1.f / 1024.f);
  const float var = s2 * (1.f / 1024.f) - mu * mu;
  const float rstd = rsqrtf(var + 1e-5f);
  f32x4 gv = *(const f32x4*)&gg[t * 4];
  f32x4 bv = *(const f32x4*)&bb[t * 4];
  f32x4 ov;
  for (int i = 0; i < 4; ++i) ov[i] = (x[i] - mu) * rstd * gv[i] + bv[i];
  *(f32x4*)&out[(size_t)row * 1024 + t * 4] = ov;
}

extern "C" void kernel_launch(void* const* d_in, const int* in_sizes, int n_in,
                              void* d_out, int out_size, void* d_ws, size_t ws_size,
                              hipStream_t stream) {
  (void)in_sizes; (void)n_in; (void)out_size; (void)ws_size;
  const float* q_s = (const float*)d_in[0];
  const float* pos = (const float*)d_in[1];
  const float* Wq = (const float*)d_in[2];
  const float* Wk = (const float*)d_in[3];
  const float* Wv = (const float*)d_in[4];
  const float* Wo = (const float*)d_in[5];
  const float* bo = (const float*)d_in[6];
  const float* lng = (const float*)d_in[7];
  const float* lnb = (const float*)d_in[8];
  float* out = (float*)d_out;

  u16* ws = (u16*)d_ws;
  const size_t MB1 = 1024 * 1024;  // elements
  u16* WT  = ws;                   // 4 x 1M bf16 (Wq^T,Wk^T,Wv^T,Wo^T)
  u16* Xbf = ws + 4 * MB1;         // q_s as bf16
  u16* Qh  = Xbf + 4 * MB1;        // [32][2048][64]
  u16* Kh  = Qh + 4 * MB1;
  u16* Vh  = Kh + 4 * MB1;
  u16* Vt  = Vh + 4 * MB1;         // [32][64][2048]
  u16* Oh  = Vt + 4 * MB1;         // [32][2048][64]
  float* Xb = (float*)Qh;          // f32 pre-LN x, aliases Qh+Kh (dead after attn)

  dim3 blk(256);
  k_cvt<<<dim3(2048), blk, 0, stream>>>(q_s, Xbf, 4 * MB1 / 8);
  k_transpose1024<<<dim3(16, 16), blk, 0, stream>>>(Wq, WT);
  k_transpose1024<<<dim3(16, 16), blk, 0, stream>>>(Wk, WT + MB1);
  k_transpose1024<<<dim3(16, 16), blk, 0, stream>>>(Wv, WT + 2 * MB1);
  k_transpose1024<<<dim3(16, 16), blk, 0, stream>>>(Wo, WT + 3 * MB1);
  k_qkv_gemm<<<dim3(24, 32), blk, 0, stream>>>(Xbf, WT, pos, Qh, Kh, Vh);
  k_transpose_v<<<dim3(32, 32), blk, 0, stream>>>(Vh, Vt);
  k_attn<<<dim3(1024), blk, 0, stream>>>(Qh, Kh, Vt, Oh);
  k_out_gemm<<<dim3(8, 32), blk, 0, stream>>>(Oh, WT + 3 * MB1, bo, q_s, Xb);
  k_ln<<<4096, blk, 0, stream>>>(Xb, lng, lnb, out);
}

// Round 4
// 210.944 us; speedup vs baseline: 1.6606x; 1.1280x over previous
//
#include <hip/hip_runtime.h>
#include <hip/hip_bf16.h>
#include <stdint.h>

typedef unsigned short u16;
typedef unsigned int u32;
typedef short s16x8 __attribute__((ext_vector_type(8)));
typedef short s16x4 __attribute__((ext_vector_type(4)));
typedef float f32x4 __attribute__((ext_vector_type(4)));

#define MFMA(a, b, c) __builtin_amdgcn_mfma_f32_16x16x32_bf16((a), (b), (c), 0, 0, 0)

__device__ __forceinline__ u16 f2bf_rte(float f) {
  __hip_bfloat16 h = __float2bfloat16(f);
  u16 u;
  __builtin_memcpy(&u, &h, 2);
  return u;
}

__device__ __forceinline__ void gload16(const u16* g, u16* l) {
  __builtin_amdgcn_global_load_lds((const __attribute__((address_space(1))) u32*)g,
                                   (__attribute__((address_space(3))) u32*)l, 16, 0, 0);
}

// ---------------- f32 -> bf16 elementwise (q_s) ----------------
__global__ __launch_bounds__(256) void k_cvt(const float* __restrict__ in,
                                             u16* __restrict__ out, int n8) {
  int i = blockIdx.x * 256 + threadIdx.x;
  if (i >= n8) return;
  const f32x4* p = (const f32x4*)(in + (size_t)i * 8);
  f32x4 a = p[0], b = p[1];
  s16x8 o;
  for (int k = 0; k < 4; ++k) o[k] = (short)f2bf_rte(a[k]);
  for (int k = 0; k < 4; ++k) o[4 + k] = (short)f2bf_rte(b[k]);
  *(s16x8*)(out + (size_t)i * 8) = o;
}

// ---------------- transpose 4x 1024x1024 f32 weights -> bf16 (one launch) ----------------
__global__ __launch_bounds__(256) void k_transpose_w(const float* __restrict__ W0,
                                                     const float* __restrict__ W1,
                                                     const float* __restrict__ W2,
                                                     const float* __restrict__ W3,
                                                     u16* __restrict__ out) {
  const int z = blockIdx.z;
  const float* in = (z == 0) ? W0 : (z == 1) ? W1 : (z == 2) ? W2 : W3;
  u16* o = out + (size_t)z * 1024 * 1024;
  __shared__ u16 tile[64][65];
  const int t = threadIdx.x, tx = t & 63, ty = t >> 6;
  const int r0 = blockIdx.y * 64, c0 = blockIdx.x * 64;
  for (int rr = 0; rr < 16; ++rr) {
    int row = rr * 4 + ty;
    tile[row][tx] = f2bf_rte(in[(size_t)(r0 + row) * 1024 + c0 + tx]);
  }
  __syncthreads();
  for (int rr = 0; rr < 16; ++rr) {
    int row = rr * 4 + ty;
    o[(size_t)(c0 + row) * 1024 + r0 + tx] = tile[tx][row];
  }
}

// ---------------- transpose V [bh][2048][64] -> Vt[bh][64][2048] ----------------
__global__ __launch_bounds__(256) void k_transpose_v(const u16* __restrict__ V,
                                                     u16* __restrict__ Vt) {
  __shared__ u16 tile[64][65];
  const int t = threadIdx.x, tx = t & 63, ty = t >> 6;
  const int j0 = blockIdx.x * 64;
  const int bh = blockIdx.y;
  const u16* src = V + (size_t)bh * 2048 * 64;
  u16* dst = Vt + (size_t)bh * 64 * 2048;
  for (int rr = 0; rr < 16; ++rr) {
    int row = rr * 4 + ty;
    tile[row][tx] = src[(size_t)(j0 + row) * 64 + tx];
  }
  __syncthreads();
  for (int rr = 0; rr < 16; ++rr) {
    int d = rr * 4 + ty;
    dst[(size_t)d * 2048 + j0 + tx] = tile[tx][d];
  }
}

// ---------------- fused QKV GEMM (global_load_lds staging) ----------------
// Q pre-scaled by 0.125*log2(e) (exp2-domain attention). K gets pos added.
__global__ __launch_bounds__(256) void k_qkv_gemm(const u16* __restrict__ X,
                                                  const u16* __restrict__ WT,
                                                  const float* __restrict__ pos,
                                                  u16* __restrict__ Qh,
                                                  u16* __restrict__ Kh,
                                                  u16* __restrict__ Vh) {
  __shared__ u16 As[128 * 32];
  __shared__ u16 Bs[128 * 32];
  const int t = threadIdx.x;
  const int lane = t & 63, wid = t >> 6;
  const int wr = wid >> 1, wc = wid & 1;
  const int g = lane >> 4, lr = lane & 15;
  const int m0 = blockIdx.y * 128, n0 = blockIdx.x * 128;

  const int srcRow = wid * 16 + (lane >> 2);
  const int srcK = (lane & 3) * 8;
  const u16* aSrc = &X[(size_t)(m0 + srcRow) * 1024 + srcK];
  const u16* bSrc = &WT[(size_t)(n0 + srcRow) * 1024 + srcK];
  u16* aDst = &As[wid * 512];
  u16* bDst = &Bs[wid * 512];

  f32x4 acc[4][4] = {};

  for (int k0 = 0; k0 < 1024; k0 += 32) {
    gload16(aSrc + k0, aDst);
    gload16(aSrc + 64 * 1024 + k0, aDst + 2048);
    gload16(bSrc + k0, bDst);
    gload16(bSrc + 64 * 1024 + k0, bDst + 2048);
    __syncthreads();
    s16x8 a[4], b[4];
    for (int mi = 0; mi < 4; ++mi) a[mi] = *(const s16x8*)&As[(wr * 64 + mi * 16 + lr) * 32 + g * 8];
    for (int nj = 0; nj < 4; ++nj) b[nj] = *(const s16x8*)&Bs[(wc * 64 + nj * 16 + lr) * 32 + g * 8];
    for (int mi = 0; mi < 4; ++mi)
      for (int nj = 0; nj < 4; ++nj)
        acc[mi][nj] = MFMA(a[mi], b[nj], acc[mi][nj]);
    __syncthreads();
  }

  const float QSCALE = 0.125f * 1.44269504f;
  for (int mi = 0; mi < 4; ++mi) {
    for (int nj = 0; nj < 4; ++nj) {
      const int n_g = n0 + wc * 64 + nj * 16 + lr;
      const int buf = n_g >> 10;       // 0=Q 1=K 2=V
      const int col = n_g & 1023;
      const int h = col >> 6, d = col & 63;
      u16* dst = (buf == 0) ? Qh : ((buf == 1) ? Kh : Vh);
      for (int r = 0; r < 4; ++r) {
        const int row = m0 + wr * 64 + mi * 16 + g * 4 + r;  // 0..4095
        const int b = row >> 11, n = row & 2047;
        float v = acc[mi][nj][r];
        if (buf == 1) v += pos[(size_t)row * 1024 + col];
        if (buf == 0) v *= QSCALE;
        dst[(size_t)((b * 16 + h) * 2048 + n) * 64 + d] = f2bf_rte(v);
      }
    }
  }
}

// ---------------- flash attention: dbuf K/V, async stage, defer-max ----------------
__global__ __launch_bounds__(256) void k_attn(const u16* __restrict__ Qh,
                                              const u16* __restrict__ Kh,
                                              const u16* __restrict__ Vt,
                                              u16* __restrict__ Oh) {
  const int t = threadIdx.x, lane = t & 63, wid = t >> 6;
  const int g = lane >> 4, lr = lane & 15;
  const int hid = blockIdx.x;
  const int lid = (hid & 7) * 128 + (hid >> 3);   // bijective XCD swizzle (1024 % 8 == 0)
  const int bh = lid >> 5, itile = lid & 31;
  const int i0 = itile * 64 + wid * 16;

  __shared__ char Ks[2][8192];
  __shared__ char Vs[2][8192];
  __shared__ char Ps[4][2048];
  char* Pw = Ps[wid];

  const u16* Qp = Qh + (size_t)bh * 2048 * 64;
  const u16* Kp = Kh + (size_t)bh * 2048 * 64;
  const u16* Vp = Vt + (size_t)bh * 64 * 2048;

  s16x8 aq[2];
  aq[0] = *(const s16x8*)&Qp[(size_t)(i0 + lr) * 64 + g * 8];
  aq[1] = *(const s16x8*)&Qp[(size_t)(i0 + lr) * 64 + 32 + g * 8];

  f32x4 o_acc[4] = {};
  float m_run[4], l_run[4];
  for (int r = 0; r < 4; ++r) { m_run[r] = -1e30f; l_run[r] = 0.f; }

  const int srow = t >> 3;          // 0..31
  const int sch = (t & 7) * 16;     // byte chunk
  const int swz = (srow & 7) << 4;  // (srow+32)&7 == srow&7
  const int sb0 = (srow * 128 + sch) ^ swz;
  const int sb1 = ((srow + 32) * 128 + sch) ^ swz;
  const u16* kB0 = &Kp[(size_t)srow * 64 + (sch >> 1)];
  const u16* kB1 = &Kp[(size_t)(srow + 32) * 64 + (sch >> 1)];
  const u16* vB0 = &Vp[(size_t)srow * 2048 + (sch >> 1)];
  const u16* vB1 = &Vp[(size_t)(srow + 32) * 2048 + (sch >> 1)];

  s16x8 kr0 = *(const s16x8*)kB0;
  s16x8 kr1 = *(const s16x8*)kB1;
  s16x8 vr0 = *(const s16x8*)vB0;
  s16x8 vr1 = *(const s16x8*)vB1;
  *(s16x8*)(Ks[0] + sb0) = kr0;
  *(s16x8*)(Ks[0] + sb1) = kr1;
  *(s16x8*)(Vs[0] + sb0) = vr0;
  *(s16x8*)(Vs[0] + sb1) = vr1;
  __syncthreads();

  for (int tt = 0; tt < 32; ++tt) {
    const int cur = tt & 1;
    // async-STAGE: issue next-tile global loads before compute (T14)
    if (tt < 31) {
      const int j1 = (tt + 1) * 64;
      kr0 = *(const s16x8*)(kB0 + (size_t)j1 * 64);
      kr1 = *(const s16x8*)(kB1 + (size_t)j1 * 64);
      vr0 = *(const s16x8*)(vB0 + j1);
      vr1 = *(const s16x8*)(vB1 + j1);
    }
    const char* Kc = Ks[cur];
    const char* Vc = Vs[cur];

    // ---- QK^T (logits already in log2 domain via Q pre-scale) ----
    f32x4 s[4] = {};
    __builtin_amdgcn_s_setprio(1);
    for (int jf = 0; jf < 4; ++jf) {
      const int row = jf * 16 + lr;
      const int bw = (row & 7) << 4;
      s16x8 bk0 = *(const s16x8*)(Kc + ((row * 128 + g * 16) ^ bw));
      s16x8 bk1 = *(const s16x8*)(Kc + ((row * 128 + 64 + g * 16) ^ bw));
      s[jf] = MFMA(aq[0], bk0, s[jf]);
      s[jf] = MFMA(aq[1], bk1, s[jf]);
    }
    __builtin_amdgcn_s_setprio(0);

    // ---- online softmax with defer-max (T13) ----
    float tl[4];
    for (int r = 0; r < 4; ++r)
      tl[r] = fmaxf(fmaxf(s[0][r], s[1][r]), fmaxf(s[2][r], s[3][r]));
    int ok = (tl[0] <= m_run[0] + 8.f) & (tl[1] <= m_run[1] + 8.f) &
             (tl[2] <= m_run[2] + 8.f) & (tl[3] <= m_run[3] + 8.f);
    if (!__all(ok)) {
      for (int r = 0; r < 4; ++r) {
        float tm = tl[r];
        for (int m = 1; m < 16; m <<= 1) tm = fmaxf(tm, __shfl_xor(tm, m, 64));
        float mnew = fmaxf(m_run[r], tm);
        float alpha = __builtin_amdgcn_exp2f(m_run[r] - mnew);
        l_run[r] *= alpha;
        m_run[r] = mnew;
        for (int df = 0; df < 4; ++df) o_acc[df][r] *= alpha;
      }
    }
    float psum[4] = {0.f, 0.f, 0.f, 0.f};
    for (int jf = 0; jf < 4; ++jf)
      for (int r = 0; r < 4; ++r) {
        float p = __builtin_amdgcn_exp2f(s[jf][r] - m_run[r]);
        s[jf][r] = p;
        psum[r] += p;
      }
    for (int r = 0; r < 4; ++r) {
      float ps = psum[r];
      for (int m = 1; m < 16; m <<= 1) ps += __shfl_xor(ps, m, 64);
      l_run[r] += ps;
    }

    // ---- P -> LDS (per-wave, swizzled) ----
    for (int jf = 0; jf < 4; ++jf)
      for (int r = 0; r < 4; ++r) {
        const int row = g * 4 + r;
        *(u16*)(Pw + ((row * 128 + (jf * 16 + lr) * 2) ^ ((row & 7) << 4))) =
            f2bf_rte(s[jf][r]);
      }

    s16x8 pa[2];
    {
      const int bw = (lr & 7) << 4;
      pa[0] = *(const s16x8*)(Pw + ((lr * 128 + g * 16) ^ bw));
      pa[1] = *(const s16x8*)(Pw + ((lr * 128 + 64 + g * 16) ^ bw));
    }

    // ---- PV ----
    __builtin_amdgcn_s_setprio(1);
    for (int df = 0; df < 4; ++df) {
      const int row = df * 16 + lr;
      const int bw = (row & 7) << 4;
      s16x8 bv0 = *(const s16x8*)(Vc + ((row * 128 + g * 16) ^ bw));
      s16x8 bv1 = *(const s16x8*)(Vc + ((row * 128 + 64 + g * 16) ^ bw));
      o_acc[df] = MFMA(pa[0], bv0, o_acc[df]);
      o_acc[df] = MFMA(pa[1], bv1, o_acc[df]);
    }
    __builtin_amdgcn_s_setprio(0);

    // write next tile into the other buffer (vmcnt waited here, hidden by compute)
    if (tt < 31) {
      char* Kn = Ks[cur ^ 1];
      char* Vn = Vs[cur ^ 1];
      *(s16x8*)(Kn + sb0) = kr0;
      *(s16x8*)(Kn + sb1) = kr1;
      *(s16x8*)(Vn + sb0) = vr0;
      *(s16x8*)(Vn + sb1) = vr1;
    }
    __syncthreads();
  }

  for (int df = 0; df < 4; ++df)
    for (int r = 0; r < 4; ++r) {
      const int row = i0 + g * 4 + r;
      float v = o_acc[df][r] / l_run[r];
      Oh[(size_t)((size_t)bh * 2048 + row) * 64 + df * 16 + lr] = f2bf_rte(v);
    }
}

// ---------------- out GEMM: Oh(packed) @ Wo + bo + q_s -> X (f32) ----------------
__global__ __launch_bounds__(256) void k_out_gemm(const u16* __restrict__ Oh,
                                                  const u16* __restrict__ WTo,
                                                  const float* __restrict__ bo,
                                                  const float* __restrict__ qs,
                                                  float* __restrict__ X) {
  __shared__ u16 As[128 * 32];
  __shared__ u16 Bs[128 * 32];
  const int t = threadIdx.x;
  const int lane = t & 63, wid = t >> 6;
  const int wr = wid >> 1, wc = wid & 1;
  const int g = lane >> 4, lr = lane & 15;
  const int m0 = blockIdx.y * 128, n0 = blockIdx.x * 128;

  const int srcRow = wid * 16 + (lane >> 2);
  const int srcK = (lane & 3) * 8;
  const int rg = m0 + srcRow, bb0 = rg >> 11, nn0 = rg & 2047;
  const int rg2 = rg + 64, bb2 = rg2 >> 11, nn2 = rg2 & 2047;
  const u16* bSrc = &WTo[(size_t)(n0 + srcRow) * 1024 + srcK];
  u16* aDst = &As[wid * 512];
  u16* bDst = &Bs[wid * 512];

  f32x4 acc[4][4] = {};

  for (int k0 = 0; k0 < 1024; k0 += 32) {
    const int h = k0 >> 6, d = (k0 & 63) + srcK;
    gload16(&Oh[((size_t)(bb0 * 16 + h) * 2048 + nn0) * 64 + d], aDst);
    gload16(&Oh[((size_t)(bb2 * 16 + h) * 2048 + nn2) * 64 + d], aDst + 2048);
    gload16(bSrc + k0, bDst);
    gload16(bSrc + 64 * 1024 + k0, bDst + 2048);
    __syncthreads();
    s16x8 a[4], b[4];
    for (int mi = 0; mi < 4; ++mi) a[mi] = *(const s16x8*)&As[(wr * 64 + mi * 16 + lr) * 32 + g * 8];
    for (int nj = 0; nj < 4; ++nj) b[nj] = *(const s16x8*)&Bs[(wc * 64 + nj * 16 + lr) * 32 + g * 8];
    for (int mi = 0; mi < 4; ++mi)
      for (int nj = 0; nj < 4; ++nj)
        acc[mi][nj] = MFMA(a[mi], b[nj], acc[mi][nj]);
    __syncthreads();
  }

  for (int mi = 0; mi < 4; ++mi) {
    for (int nj = 0; nj < 4; ++nj) {
      const int col = n0 + wc * 64 + nj * 16 + lr;
      for (int r = 0; r < 4; ++r) {
        const int row = m0 + wr * 64 + mi * 16 + g * 4 + r;
        float v = acc[mi][nj][r] + bo[col] + qs[(size_t)row * 1024 + col];
        X[(size_t)row * 1024 + col] = v;
      }
    }
  }
}

// ---------------- LayerNorm rows of 1024 (f32 in, f32 out) ----------------
__global__ __launch_bounds__(256) void k_ln(const float* __restrict__ X,
                                            const float* __restrict__ gg,
                                            const float* __restrict__ bb,
                                            float* __restrict__ out) {
  const int row = blockIdx.x, t = threadIdx.x;
  const int wid = t >> 6, lane = t & 63;
  const float* xr = X + (size_t)row * 1024;
  f32x4 x = *(const f32x4*)&xr[t * 4];
  float s1 = x[0] + x[1] + x[2] + x[3];
  float s2 = x[0] * x[0] + x[1] * x[1] + x[2] * x[2] + x[3] * x[3];
  for (int off = 32; off > 0; off >>= 1) {
    s1 += __shfl_down(s1, off, 64);
    s2 += __shfl_down(s2, off, 64);
  }
  __shared__ float red[2][4];
  if (lane == 0) { red[0][wid] = s1; red[1][wid] = s2; }
  __syncthreads();
  s1 = red[0][0] + red[0][1] + red[0][2] + red[0][3];
  s2 = red[1][0] + red[1][1] + red[1][2] + red[1][3];
  const float mu = s1 * (1.f / 1024.f);
  const float var = s2 * (1.f / 1024.f) - mu * mu;
  const float rstd = rsqrtf(var + 1e-5f);
  f32x4 gv = *(const f32x4*)&gg[t * 4];
  f32x4 bv = *(const f32x4*)&bb[t * 4];
  f32x4 ov;
  for (int i = 0; i < 4; ++i) ov[i] = (x[i] - mu) * rstd * gv[i] + bv[i];
  *(f32x4*)&out[(size_t)row * 1024 + t * 4] = ov;
}

extern "C" void kernel_launch(void* const* d_in, const int* in_sizes, int n_in,
                              void* d_out, int out_size, void* d_ws, size_t ws_size,
                              hipStream_t stream) {
  (void)in_sizes; (void)n_in; (void)out_size; (void)ws_size;
  const float* q_s = (const float*)d_in[0];
  const float* pos = (const float*)d_in[1];
  const float* Wq = (const float*)d_in[2];
  const float* Wk = (const float*)d_in[3];
  const float* Wv = (const float*)d_in[4];
  const float* Wo = (const float*)d_in[5];
  const float* bo = (const float*)d_in[6];
  const float* lng = (const float*)d_in[7];
  const float* lnb = (const float*)d_in[8];
  float* out = (float*)d_out;

  u16* ws = (u16*)d_ws;
  const size_t MB1 = 1024 * 1024;  // elements
  u16* WT  = ws;                   // 4 x 1M bf16 (Wq^T,Wk^T,Wv^T,Wo^T)
  u16* Xbf = ws + 4 * MB1;         // q_s as bf16
  u16* Qh  = Xbf + 4 * MB1;        // [32][2048][64]
  u16* Kh  = Qh + 4 * MB1;
  u16* Vh  = Kh + 4 * MB1;
  u16* Vt  = Vh + 4 * MB1;         // [32][64][2048]
  u16* Oh  = Vt + 4 * MB1;         // [32][2048][64]
  float* Xb = (float*)Qh;          // f32 pre-LN x, aliases Qh+Kh (dead after attn)

  dim3 blk(256);
  k_cvt<<<dim3(2048), blk, 0, stream>>>(q_s, Xbf, 4 * MB1 / 8);
  k_transpose_w<<<dim3(16, 16, 4), blk, 0, stream>>>(Wq, Wk, Wv, Wo, WT);
  k_qkv_gemm<<<dim3(24, 32), blk, 0, stream>>>(Xbf, WT, pos, Qh, Kh, Vh);
  k_transpose_v<<<dim3(32, 32), blk, 0, stream>>>(Vh, Vt);
  k_attn<<<dim3(1024), blk, 0, stream>>>(Qh, Kh, Vt, Oh);
  k_out_gemm<<<dim3(8, 32), blk, 0, stream>>>(Oh, WT + 3 * MB1, bo, q_s, Xb);
  k_ln<<<4096, blk, 0, stream>>>(Xb, lng, lnb, out);
}